// Round 1
// baseline (249.982 us; speedup 1.0000x reference)
//
#include <hip/hip_runtime.h>
#include <hip/hip_bf16.h>
#include <stdint.h>

#define B_ 16
#define N_ 512
#define E_ 8192
#define D_ 256

// ---- workspace layout (float offsets) ----
constexpr int OFF_OBJ = 16;                       // flags live in ws[0..1] (as int)
constexpr int OFF_WN  = OFF_OBJ + B_*N_*D_;
constexpr int OFF_WE  = OFF_WN + D_*D_;
constexpr int OFF_WA  = OFF_WE + D_*D_;           // 769 used, padded 1024
constexpr int OFF_GAM = OFF_WA + 1024;
constexpr int OFF_BET = OFF_GAM + D_;
constexpr int OFF_SIM = OFF_BET + D_;
constexpr int OFF_TN  = OFF_SIM + B_*E_;
constexpr int OFF_VE  = OFF_TN + B_*N_*D_;
constexpr int OFF_S1  = OFF_VE + D_;
constexpr int OFF_S2  = OFF_S1 + B_*N_;
constexpr int OFF_SC  = OFF_S2 + B_*N_;
constexpr int OFF_WT  = OFF_SC + B_*E_;
constexpr int CONV_TOTAL = B_*N_*D_ + D_*D_ + D_*D_ + 769 + D_ + D_ + B_*E_;

__device__ __forceinline__ float bf2f(uint16_t u) {
    union { uint32_t i; float f; } v; v.i = ((uint32_t)u) << 16; return v.f;
}

__device__ __forceinline__ float loadF(const void* p, int i, int isBF) {
    if (isBF) return __bfloat162float(((const __hip_bfloat16*)p)[i]);
    return ((const float*)p)[i];
}

// mask layouts: 0=u8/bool, 1=int32, 2=bf16, 3=f32
__device__ __forceinline__ bool readMask(const void* p, int i, int ml) {
    if (ml == 0) return ((const uint8_t*)p)[i] != 0;
    if (ml == 1) return ((const int*)p)[i] != 0;
    if (ml == 2) return (((const uint16_t*)p)[i] & 0x7FFFu) != 0;
    return (((const uint32_t*)p)[i] & 0x7FFFFFFFu) != 0;
}

// ---- K0: detect float dtype (bf16 vs f32) and mask storage layout ----
__global__ void k_detect(const uint32_t* objw, const uint32_t* emaskw, int* flags) {
    __shared__ int s_insane;
    __shared__ int s_ok[3];  // i32, f32, bf16 all-compatible votes
    int t = threadIdx.x;
    if (t == 0) { s_insane = 0; s_ok[0] = 1; s_ok[1] = 1; s_ok[2] = 1; }
    __syncthreads();
    {   // obj_nodes ~ N(0,1): if buffer is f32, its low halfwords viewed as bf16
        // have random exponents -> "insane" magnitudes. If bf16, ~none insane.
        uint32_t x = objw[t];
        int insane = 0;
        #pragma unroll
        for (int h = 0; h < 2; ++h) {
            uint32_t v = (h ? (x >> 16) : x) & 0xFFFFu;
            uint32_t e = (v >> 7) & 0xFFu;
            if ((v & 0x7FFFu) != 0 && (e < 107u || e > 147u)) insane++;
        }
        if (insane) atomicAdd(&s_insane, insane);
    }
    {
        int i32ok = 1, f32ok = 1, bfok = 1;
        for (int i = t; i < 1024; i += 256) {
            uint32_t x = emaskw[i];
            if (!(x <= 1u)) i32ok = 0;
            if (!(x == 0u || x == 0x3F800000u)) f32ok = 0;
            uint32_t lo = x & 0xFFFFu, hi = x >> 16;
            if (!((lo == 0u || lo == 0x3F80u) && (hi == 0u || hi == 0x3F80u))) bfok = 0;
        }
        if (!i32ok) atomicAnd(&s_ok[0], 0);
        if (!f32ok) atomicAnd(&s_ok[1], 0);
        if (!bfok)  atomicAnd(&s_ok[2], 0);
    }
    __syncthreads();
    if (t == 0) {
        flags[0] = (s_insane > 64) ? 0 : 1;   // 1 = floats are bf16
        int ml = 0;
        if (s_ok[0]) ml = 1; else if (s_ok[1]) ml = 3; else if (s_ok[2]) ml = 2;
        flags[1] = ml;
    }
}

// ---- K1: convert all small float inputs to f32 scratch (one code path after) ----
__global__ void k_convert(const void* obj, const void* wn, const void* we, const void* wa,
                          const void* gam, const void* bet, const void* sim, float* ws) {
    int isBF = ((const int*)ws)[0];
    int stride = gridDim.x * blockDim.x;
    for (int i = blockIdx.x * blockDim.x + threadIdx.x; i < CONV_TOTAL; i += stride) {
        int j = i;
        if (j < B_*N_*D_) { ws[OFF_OBJ + j] = loadF(obj, j, isBF); continue; }
        j -= B_*N_*D_;
        if (j < D_*D_)    { ws[OFF_WN + j]  = loadF(wn, j, isBF); continue; }
        j -= D_*D_;
        if (j < D_*D_)    { ws[OFF_WE + j]  = loadF(we, j, isBF); continue; }
        j -= D_*D_;
        if (j < 769)      { ws[OFF_WA + j]  = loadF(wa, j, isBF); continue; }
        j -= 769;
        if (j < D_)       { ws[OFF_GAM + j] = loadF(gam, j, isBF); continue; }
        j -= D_;
        if (j < D_)       { ws[OFF_BET + j] = loadF(bet, j, isBF); continue; }
        j -= D_;
        ws[OFF_SIM + j] = loadF(sim, j, isBF);
    }
}

// ---- K1b: v_edge[k] = sum_o wa3[o] * w_edge[o][k]  (kills the (B,E,D)x(D,D) GEMM) ----
__global__ void k_vedge(float* ws) {
    int t = threadIdx.x;
    const float* we  = ws + OFF_WE;
    const float* wa3 = ws + OFF_WA + 513;
    float a0 = 0.f, a1 = 0.f, a2 = 0.f, a3 = 0.f;
    for (int d = 0; d < D_; d += 4) {
        a0 += wa3[d]   * we[(d)   * D_ + t];
        a1 += wa3[d+1] * we[(d+1) * D_ + t];
        a2 += wa3[d+2] * we[(d+2) * D_ + t];
        a3 += wa3[d+3] * we[(d+3) * D_ + t];
    }
    ws[OFF_VE + t] = (a0 + a1) + (a2 + a3);
}

// ---- K2: tn = obj @ w_node^T   (8192x256 @ 256x256), W^T tiles in LDS ----
__global__ __launch_bounds__(256) void k_nodefc(float* ws) {
    __shared__ float wt[32][257];  // wt[kl][o], stride 257 -> conflict-free
    const float* obj = ws + OFF_OBJ;
    const float* wn  = ws + OFF_WN;
    float* tn = ws + OFF_TN;
    int t = threadIdx.x;
    int row0 = blockIdx.x * 16;
    float acc[16];
    #pragma unroll
    for (int r = 0; r < 16; ++r) acc[r] = 0.f;
    for (int kt = 0; kt < 8; ++kt) {
        __syncthreads();
        #pragma unroll
        for (int i = 0; i < 32; ++i) {
            int idx = t + i * 256;
            int o = idx >> 5, kl = idx & 31;
            wt[kl][o] = wn[o * D_ + kt * 32 + kl];
        }
        __syncthreads();
        float wreg[32];
        #pragma unroll
        for (int kl = 0; kl < 32; ++kl) wreg[kl] = wt[kl][t];
        for (int r = 0; r < 16; ++r) {
            const float* xr = obj + (row0 + r) * D_ + kt * 32;  // block-uniform -> s_loads
            float a = 0.f;
            #pragma unroll
            for (int kl = 0; kl < 32; ++kl) a += xr[kl] * wreg[kl];
            acc[r] += a;
        }
    }
    #pragma unroll
    for (int r = 0; r < 16; ++r) tn[(row0 + r) * D_ + t] = acc[r];
}

// ---- K3: s1[b,n]=dot(tn row, wa1), s2=dot(tn row, wa2) ----
__global__ __launch_bounds__(256) void k_s1s2(float* ws) {
    const float* tn = ws + OFF_TN;
    const float* wa = ws + OFF_WA;
    int gid = blockIdx.x * blockDim.x + threadIdx.x;
    int wave = gid >> 6, lane = gid & 63;
    if (wave >= B_ * N_) return;
    float4 x  = *(const float4*)(tn + (size_t)wave * D_ + lane * 4);
    float4 a1 = *(const float4*)(wa + lane * 4);
    float4 a2 = *(const float4*)(wa + D_ + lane * 4);
    float d1 = x.x*a1.x + x.y*a1.y + x.z*a1.z + x.w*a1.w;
    float d2 = x.x*a2.x + x.y*a2.y + x.z*a2.z + x.w*a2.w;
    #pragma unroll
    for (int off = 32; off > 0; off >>= 1) {
        d1 += __shfl_xor(d1, off);
        d2 += __shfl_xor(d2, off);
    }
    if (lane == 0) { ws[OFF_S1 + wave] = d1; ws[OFF_S2 + wave] = d2; }
}

// ---- K4: raw edge scores (wave per edge), streams pred_emb once ----
__global__ __launch_bounds__(256) void k_scores(const void* pred, const int2* rel,
                                                const void* emask, float* ws) {
    const int* flags = (const int*)ws;
    int isBF = flags[0], ml = flags[1];
    int gid = blockIdx.x * blockDim.x + threadIdx.x;
    int gw = gid >> 6, lane = gid & 63;
    if (gw >= B_ * E_) return;
    int b = gw >> 13;
    float4 ve4 = *(const float4*)(ws + OFF_VE + lane * 4);
    float dot;
    if (isBF) {
        ushort4 v = *(const ushort4*)((const uint16_t*)pred + (size_t)gw * D_ + lane * 4);
        dot = bf2f(v.x)*ve4.x + bf2f(v.y)*ve4.y + bf2f(v.z)*ve4.z + bf2f(v.w)*ve4.w;
    } else {
        float4 v = *(const float4*)((const float*)pred + (size_t)gw * D_ + lane * 4);
        dot = v.x*ve4.x + v.y*ve4.y + v.z*ve4.z + v.w*ve4.w;
    }
    #pragma unroll
    for (int off = 32; off > 0; off >>= 1) dot += __shfl_xor(dot, off);
    if (lane == 0) {
        int2 sd = rel[gw];
        float s = dot + ws[OFF_S1 + b * N_ + sd.x] + ws[OFF_S2 + b * N_ + sd.y]
                + ws[OFF_SIM + gw] * ws[OFF_WA + 512];
        s = (s > 0.f) ? s : 0.01f * s;                 // leaky_relu, slope 0.01
        ws[OFF_SC + gw] = readMask(emask, gw, ml) ? s : -1e9f;
    }
}

// ---- K5: per-batch softmax over 8192 edges ----
__global__ __launch_bounds__(1024) void k_softmax(float* ws) {
    __shared__ float red[1024];
    int b = blockIdx.x, t = threadIdx.x;
    const float* sc = ws + OFF_SC + b * E_;
    float* wt = ws + OFF_WT + b * E_;
    float loc[8];
    float mx = -3e38f;
    #pragma unroll
    for (int i = 0; i < 8; ++i) { loc[i] = sc[t + i * 1024]; mx = fmaxf(mx, loc[i]); }
    red[t] = mx; __syncthreads();
    for (int s = 512; s > 0; s >>= 1) { if (t < s) red[t] = fmaxf(red[t], red[t + s]); __syncthreads(); }
    float M = red[0];
    __syncthreads();
    float sum = 0.f;
    #pragma unroll
    for (int i = 0; i < 8; ++i) { loc[i] = __expf(loc[i] - M); sum += loc[i]; }
    red[t] = sum; __syncthreads();
    for (int s = 512; s > 0; s >>= 1) { if (t < s) red[t] += red[t + s]; __syncthreads(); }
    float inv = 1.f / red[0];
    #pragma unroll
    for (int i = 0; i < 8; ++i) wt[t + i * 1024] = loc[i] * inv;
}

// ---- K6: scatter-add (LDS accum per 32-node slice) fused with node-mask + LayerNorm ----
__global__ __launch_bounds__(256) void k_scatter_ln(const int2* rel, const void* nmask,
                                                    const float* wsc, void* out) {
    __shared__ float acc[32][256];   // d = lane + 64*j -> ds_add conflict-free
    const float* ws = wsc;
    const int* flags = (const int*)ws;
    int isBF = flags[0], ml = flags[1];
    int t = threadIdx.x, w = t >> 6, lane = t & 63;
    int b = blockIdx.x >> 4, nq = blockIdx.x & 15, n0 = nq * 32;
    #pragma unroll
    for (int i = 0; i < 32; ++i) {
        int idx = t + i * 256;
        acc[idx >> 8][idx & 255] = 0.f;
    }
    __syncthreads();
    const float* tn   = ws + OFF_TN + (size_t)b * N_ * D_;
    const float* wgt  = ws + OFF_WT + b * E_;
    const int2* relb  = rel + b * E_;
    for (int base = w * 64; base < E_; base += 256) {
        int e = base + lane;
        int2 sd = relb[e];
        float ww = wgt[e];
        bool act = (ww != 0.f) && (sd.y >= n0) && (sd.y < n0 + 32);
        unsigned long long mb = __ballot(act);
        while (mb) {
            int l = __builtin_ctzll(mb);
            mb &= mb - 1;
            int s  = __shfl(sd.x, l);
            int dn = __shfl(sd.y, l) - n0;
            float wv = __shfl(ww, l);
            const float* src = tn + (size_t)s * D_;
            #pragma unroll
            for (int j = 0; j < 4; ++j) {
                atomicAdd(&acc[dn][lane + 64 * j], wv * src[lane + 64 * j]);
            }
        }
    }
    __syncthreads();
    const float* gam = ws + OFF_GAM;
    const float* bet = ws + OFF_BET;
    for (int node = w; node < 32; node += 4) {
        int n = n0 + node;
        float mk = readMask(nmask, b * N_ + n, ml) ? 1.f : 0.f;
        float v[4]; float sum = 0.f, sq = 0.f;
        #pragma unroll
        for (int j = 0; j < 4; ++j) {
            v[j] = acc[node][lane + 64 * j] * mk;
            sum += v[j]; sq += v[j] * v[j];
        }
        #pragma unroll
        for (int off = 32; off > 0; off >>= 1) {
            sum += __shfl_xor(sum, off);
            sq  += __shfl_xor(sq, off);
        }
        float mu  = sum * (1.f / 256.f);
        float var = fmaxf(sq * (1.f / 256.f) - mu * mu, 0.f);
        float rs  = rsqrtf(var + 1e-5f);
        size_t ro = ((size_t)(b * N_ + n)) * D_;
        if (isBF) {
            __hip_bfloat16* o = (__hip_bfloat16*)out + ro;
            #pragma unroll
            for (int j = 0; j < 4; ++j) {
                int d = lane + 64 * j;
                o[d] = __float2bfloat16((v[j] - mu) * rs * gam[d] + bet[d]);
            }
        } else {
            float* o = (float*)out + ro;
            #pragma unroll
            for (int j = 0; j < 4; ++j) {
                int d = lane + 64 * j;
                o[d] = (v[j] - mu) * rs * gam[d] + bet[d];
            }
        }
    }
}

extern "C" void kernel_launch(void* const* d_in, const int* in_sizes, int n_in,
                              void* d_out, int out_size, void* d_ws, size_t ws_size,
                              hipStream_t stream) {
    (void)in_sizes; (void)n_in; (void)out_size; (void)ws_size;
    const void* obj   = d_in[0];
    const void* pred  = d_in[1];
    const int2* rel   = (const int2*)d_in[2];
    const void* sim   = d_in[3];
    const void* nmask = d_in[4];
    const void* emask = d_in[5];
    const void* wn    = d_in[6];
    const void* we    = d_in[7];
    const void* wa    = d_in[8];
    const void* gam   = d_in[9];
    const void* bet   = d_in[10];
    float* ws = (float*)d_ws;

    k_detect<<<1, 256, 0, stream>>>((const uint32_t*)obj, (const uint32_t*)emask, (int*)d_ws);
    k_convert<<<2048, 256, 0, stream>>>(obj, wn, we, wa, gam, bet, sim, ws);
    k_vedge<<<1, 256, 0, stream>>>(ws);
    k_nodefc<<<512, 256, 0, stream>>>(ws);
    k_s1s2<<<2048, 256, 0, stream>>>(ws);
    k_scores<<<(B_ * E_) / 4, 256, 0, stream>>>(pred, rel, emask, ws);
    k_softmax<<<16, 1024, 0, stream>>>(ws);
    k_scatter_ln<<<256, 256, 0, stream>>>(rel, nmask, ws, d_out);
}